// Round 11
// baseline (1405.958 us; speedup 1.0000x reference)
//
#include <hip/hip_runtime.h>

static constexpr int B = 32, N = 2048, BN = B * N;

#define DEV static __device__ __forceinline__

typedef _Float16 half_t;
typedef __attribute__((ext_vector_type(8))) _Float16 half8;
typedef __attribute__((ext_vector_type(4))) _Float16 half4;
typedef __attribute__((ext_vector_type(4))) float f32x4;
typedef unsigned long long u64;

DEV float lk(float v) { return v >= 0.f ? v : 0.01f * v; }
DEV bool lexlt(float d1, int j1, float d2, int j2) {
    return d1 < d2 || (d1 == d2 && j1 < j2);
}

DEV unsigned int mono(float f) {
    unsigned int b = __float_as_uint(f);
    return b ^ ((unsigned int)((int)b >> 31) | 0x80000000u);
}
DEV float unmono(unsigned int v) {
    unsigned int b = (v & 0x80000000u) ? (v & 0x7fffffffu) : ~v;
    return __uint_as_float(b);
}
// packed key: (mono(d) << 32) | j  — u64 '<' is EXACTLY lexlt(d,j) for j>=0.
DEV u64 pk(float d, int j) {
    return ((u64)mono(d) << 32) | (unsigned int)j;
}
static constexpr u64 KINIT = 0xFF800000ull << 32 | 0x7fffffffull;  // (inf, 0x7fffffff)

DEV int mbcnt64(unsigned long long m) {
    return __builtin_amdgcn_mbcnt_hi((unsigned)(m >> 32),
                                     __builtin_amdgcn_mbcnt_lo((unsigned)m, 0));
}
// exact reference expression: (sa+sb) - 2*dot  (sb precomputed, bit-identical)
DEV float dist4s(float4 a, float sa, float4 b, float sb) {
    float dt = fmaf(a.x, b.x, fmaf(a.y, b.y, fmaf(a.z, b.z, a.w * b.w)));
    return (sa + sb) - 2.f * dt;
}

// ---------------------------------------------------------------- build xx (+ sq norms)
__global__ __launch_bounds__(256) void k_build_xx(const float* __restrict__ x,
                                                  const float* __restrict__ pos,
                                                  float* __restrict__ xx,
                                                  float* __restrict__ sq) {
    int i = blockIdx.x * 256 + threadIdx.x;
    if (i < BN) {
        float4 v;
        v.x = x[i];
        v.y = pos[3 * i + 0];
        v.z = pos[3 * i + 1];
        v.w = pos[3 * i + 2];
        ((float4*)xx)[i] = v;
        sq[i] = fmaf(v.x, v.x, fmaf(v.y, v.y, fmaf(v.z, v.z, v.w * v.w)));
    }
}

// ---------------------------------------- per-graph exact coordinate-duplicate scan
// dupflag[g] != 0 iff some coordinate value appears in >=2 nodes of graph g
// (exact bit-level detection; -0 canonicalized to +0 since -0.f == +0.f;
//  NaN patterns conservatively flagged toward the slow path).
__global__ __launch_bounds__(256) void k_dupscan(const float* __restrict__ xx,
                                                 unsigned int* __restrict__ dupflag) {
    __shared__ unsigned int tab[4096];
    __shared__ unsigned int flag;
    int g = blockIdx.x;
    if (threadIdx.x == 0) flag = 0;
#pragma unroll 1
    for (int c = 0; c < 4; c++) {
        __syncthreads();
        for (int i = threadIdx.x; i < 4096; i += 256) tab[i] = 0xFFFFFFFFu;
        __syncthreads();
        for (int i = threadIdx.x; i < 2048; i += 256) {
            unsigned int bits = __float_as_uint(xx[(size_t)(g * 2048 + i) * 4 + c]);
            if (bits == 0x80000000u) bits = 0u;          // -0 == +0
            if (bits == 0xFFFFFFFFu) bits = 0xFFFFFFFEu; // avoid sentinel (NaN; safe dir)
            unsigned int h = (bits * 2654435761u) >> 20;
            while (true) {
                unsigned int prev = atomicCAS(&tab[h], 0xFFFFFFFFu, bits);
                if (prev == 0xFFFFFFFFu) break;
                if (prev == bits) { atomicOr(&flag, 1u); break; }
                h = (h + 1) & 4095u;
            }
        }
    }
    __syncthreads();
    if (threadIdx.x == 0) dupflag[g] = flag;
}

// ------------------------------------------------- knn(F=4) + homophily + conv1 idx
// v5: per-graph dup pre-scan gates two paths. Lean path (no coordinate dups,
// proven by k_dupscan): skip eqany tracking, skip the entire A-side radix /
// homophily machinery (counts provably 0), B-only 5-ballot radix, and a
// leader-min scatter (<=4 iters, identical j-ascending slot order). Dup path:
// original code verbatim. Outputs bit-identical either way.
__global__ __launch_bounds__(256, 8) void k_knn4(const float* __restrict__ xx,
                                                 const float* __restrict__ sq,
                                                 const unsigned int* __restrict__ dupflag,
                                                 int* __restrict__ c1idx,
                                                 unsigned int* __restrict__ hpart) {
    int gw = (blockIdx.x * 256 + threadIdx.x) >> 6;  // global row id
    int lane = threadIdx.x & 63;
    int g = gw >> 11, i = gw & 2047;
    int lane_self = i & 63, t_self = i >> 6;
    const float4* base = ((const float4*)xx) + g * N;
    const float* sqb = sq + g * N;
    float4 xi = base[i];
    float si = sqb[i];
    unsigned int uself = 0x80000000u;  // mono(+0.0f)
    bool dup = (dupflag[g] != 0);      // wave-uniform (gw uniform per wave)

    if (!dup) {
        // ---------------- lean path ----------------
        unsigned int u[32];
        unsigned int L[6];
#pragma unroll
        for (int s = 0; s < 6; s++) L[s] = 0xFFFFFFFFu;
#pragma unroll 4
        for (int t = 0; t < 32; t++) {
            float4 xj = base[lane + 64 * t];
            float sj = sqb[lane + 64 * t];
            unsigned int nv = mono(dist4s(xi, si, xj, sj));
            u[t] = nv;
#pragma unroll
            for (int s = 0; s < 6; s++) {
                unsigned int lo_ = min(L[s], nv);
                nv = max(L[s], nv);
                L[s] = lo_;
            }
        }
        unsigned int lo = L[0], hi = L[0];
#pragma unroll
        for (int o = 1; o < 64; o <<= 1) {
            lo = min(lo, (unsigned int)__shfl_xor((int)lo, o));
            hi = max(hi, (unsigned int)__shfl_xor((int)hi, o));
        }
        unsigned int cp = lo ^ hi;
        int msb = cp ? (31 - __builtin_clz(cp)) : -1;
        unsigned int vB = (msb >= 0) ? (hi & ~((2u << msb) - 1u)) : lo;
#pragma unroll 1
        for (int bit = msb; bit >= 0; --bit) {
            unsigned int cB = vB | (1u << bit);
            int cntB = 0;
#pragma unroll
            for (int s = 0; s < 5; s++) cntB += (int)__popcll(__ballot(L[s] < cB));
            if (cntB < 5) vB = cB;
        }
        unsigned int rawB = 0, eqBm = 0;
#pragma unroll
        for (int t = 0; t < 32; t++) {
            rawB |= (u[t] < vB ? 1u : 0u) << t;
            eqBm |= (u[t] == vB ? 1u : 0u) << t;
        }
        unsigned int packB = (unsigned)__popc(rawB) | ((unsigned)__popc(eqBm) << 16);
#pragma unroll
        for (int o = 1; o < 64; o <<= 1) packB += __shfl_xor(packB, o);
        int cltB = (int)(packB & 0xffffu);
        int ceqB = (int)(packB >> 16);
        int neededB = 5 - cltB;
        bool allEqB = (ceqB == neededB);

        if (lane == 0) hpart[gw] = 0u;  // proven: no coordinate dups -> counts 0

        if (allEqB) {
            // all ties take: single scatter over (rawB|eqBm), exactly 5 elements
            unsigned int mm = rawB | eqBm;
            for (int r = 0; r < 5; r++) {
                int mt = __ffs(mm) - 1;
                int key = (mt >= 0) ? ((mt << 6) | lane) : 0x7fffffff;
                int bk = key;
#pragma unroll
                for (int o = 1; o < 64; o <<= 1) bk = min(bk, __shfl_xor(bk, o));
                if (key == bk && mt >= 0) {
                    mm &= ~(1u << mt);
                    c1idx[gw * 5 + r] = lane + 64 * mt;
                }
            }
        } else {
            // strictly-less elements in j-ascending order (slots 0..cltB-1)
            unsigned int mm = rawB;
            for (int r = 0; r < cltB; r++) {
                int mt = __ffs(mm) - 1;
                int key = (mt >= 0) ? ((mt << 6) | lane) : 0x7fffffff;
                int bk = key;
#pragma unroll
                for (int o = 1; o < 64; o <<= 1) bk = min(bk, __shfl_xor(bk, o));
                if (key == bk && mt >= 0) {
                    mm &= ~(1u << mt);
                    c1idx[gw * 5 + r] = lane + 64 * mt;
                }
            }
            // tie append (by j ascending), slots cltB..4
            unsigned int em = eqBm;
            for (int r = 0; r < neededB; r++) {
                int mt = __ffs(em) - 1;
                int mj = (mt >= 0) ? (lane + 64 * mt) : 0x7fffffff;
                int bm = mj;
#pragma unroll
                for (int o = 1; o < 64; o <<= 1) bm = min(bm, __shfl_xor(bm, o));
                if (mj == bm && mt >= 0) {
                    em &= ~(1u << mt);
                    c1idx[gw * 5 + cltB + r] = bm;
                }
            }
        }
        return;
    }

    // ---------------- dup path: original code verbatim ----------------
    unsigned int u[32];
    unsigned int L[6];
    unsigned int eqany = 0;
#pragma unroll
    for (int s = 0; s < 6; s++) L[s] = 0xFFFFFFFFu;
#pragma unroll 4
    for (int t = 0; t < 32; t++) {
        float4 xj = base[lane + 64 * t];
        float sj = sqb[lane + 64 * t];
        unsigned int nv = mono(dist4s(xi, si, xj, sj));
        u[t] = nv;
        bool eq = (xj.x == xi.x) | (xj.y == xi.y) | (xj.z == xi.z) | (xj.w == xi.w);
        bool notself = (lane + 64 * t) != i;
        eqany |= (eq && notself) ? (1u << t) : 0u;
#pragma unroll
        for (int s = 0; s < 6; s++) {
            unsigned int lo_ = min(L[s], nv);
            nv = max(L[s], nv);
            L[s] = lo_;
        }
    }
    bool haveEq = (__ballot(eqany != 0) != 0ULL);

    unsigned int lo = L[0], hi = L[0];
#pragma unroll
    for (int o = 1; o < 64; o <<= 1) {
        lo = min(lo, (unsigned int)__shfl_xor((int)lo, o));
        hi = max(hi, (unsigned int)__shfl_xor((int)hi, o));
    }
    unsigned int cp = lo ^ hi;
    int msb = cp ? (31 - __builtin_clz(cp)) : -1;
    unsigned int prefix = (msb >= 0) ? (hi & ~((2u << msb) - 1u)) : lo;

    unsigned int vA = prefix, vB = prefix;
    if (haveEq) {
#pragma unroll 1
        for (int bit = msb; bit >= 0; --bit) {
            unsigned int cA = vA | (1u << bit);
            unsigned int cB = vB | (1u << bit);
            int cntA = 0, cntB = 0;
#pragma unroll
            for (int s = 0; s < 6; s++) cntA += (int)__popcll(__ballot(L[s] < cA));
#pragma unroll
            for (int s = 0; s < 5; s++) cntB += (int)__popcll(__ballot(L[s] < cB));
            cntA -= (uself < cA) ? 1 : 0;
            if (cntA < 50) vA = cA;
            if (cntB < 5) vB = cB;
        }
        if (__ballot(L[5] < vA) != 0ULL) {
            vA = prefix;
#pragma unroll 1
            for (int bit = msb; bit >= 0; --bit) {
                unsigned int c = vA | (1u << bit);
                int cnt = 0;
#pragma unroll
                for (int t = 0; t < 32; t++) cnt += (int)__popcll(__ballot(u[t] < c));
                cnt -= (uself < c) ? 1 : 0;
                if (cnt < 50) vA = c;
            }
        }
    } else {
#pragma unroll 1
        for (int bit = msb; bit >= 0; --bit) {
            unsigned int cB = vB | (1u << bit);
            int cntB = 0;
#pragma unroll
            for (int s = 0; s < 5; s++) cntB += (int)__popcll(__ballot(L[s] < cB));
            if (cntB < 5) vB = cB;
        }
    }

    unsigned int rawB = 0, eqBm = 0;
#pragma unroll
    for (int t = 0; t < 32; t++) {
        rawB |= (u[t] < vB ? 1u : 0u) << t;
        eqBm |= (u[t] == vB ? 1u : 0u) << t;
    }
    unsigned int packB = (unsigned)__popc(rawB) | ((unsigned)__popc(eqBm) << 16);

    if (haveEq) {
        unsigned int rawA = 0, eqAm = 0;
#pragma unroll
        for (int t = 0; t < 32; t++) {
            rawA |= (u[t] < vA ? 1u : 0u) << t;
            eqAm |= (u[t] == vA ? 1u : 0u) << t;
        }
        unsigned int packA = (unsigned)__popc(rawA) | ((unsigned)__popc(eqAm) << 16);
#pragma unroll
        for (int o = 1; o < 64; o <<= 1) packA += __shfl_xor(packA, o);
        int cltA = (int)(packA & 0xffffu) - ((uself < vA) ? 1 : 0);
        int ceqA = (int)(packA >> 16) - ((uself == vA) ? 1 : 0);

        int neededA = 50 - cltA;
        bool allEqA = (ceqA == neededA);
        unsigned int selAm = rawA, eqAs = eqAm;
        if (lane == lane_self) {
            selAm &= ~(1u << t_self);
            eqAs &= ~(1u << t_self);
        }
        unsigned int hm = allEqA ? (selAm | eqAs) : selAm;
        int c0 = 0, c1 = 0, c2 = 0, c3 = 0;
        unsigned int mm = hm;
        while (mm) {
            int t = __ffs(mm) - 1;
            mm &= mm - 1;
            float4 xj = base[lane + 64 * t];
            c0 += (xj.x == xi.x) ? 1 : 0;
            c1 += (xj.y == xi.y) ? 1 : 0;
            c2 += (xj.z == xi.z) ? 1 : 0;
            c3 += (xj.w == xi.w) ? 1 : 0;
        }
        if (!allEqA) {
            unsigned int em = eqAs;
            for (int r = 0; r < neededA; r++) {
                int mt = __ffs(em) - 1;
                int mj = (mt >= 0) ? (lane + 64 * mt) : 0x7fffffff;
                int bm = mj;
#pragma unroll
                for (int o = 1; o < 64; o <<= 1) bm = min(bm, __shfl_xor(bm, o));
                if (mj == bm && mt >= 0) {
                    em &= ~(1u << mt);
                    float4 xj = base[lane + 64 * mt];
                    c0 += (xj.x == xi.x) ? 1 : 0;
                    c1 += (xj.y == xi.y) ? 1 : 0;
                    c2 += (xj.z == xi.z) ? 1 : 0;
                    c3 += (xj.w == xi.w) ? 1 : 0;
                }
            }
        }
        unsigned int pc = (unsigned)c0 | ((unsigned)c1 << 8) | ((unsigned)c2 << 16) | ((unsigned)c3 << 24);
#pragma unroll
        for (int o = 1; o < 64; o <<= 1) pc += __shfl_xor(pc, o);
        if (lane == 0) hpart[gw] = pc;
    } else {
        if (lane == 0) hpart[gw] = 0u;
    }

#pragma unroll
    for (int o = 1; o < 64; o <<= 1) packB += __shfl_xor(packB, o);
    int cltB = (int)(packB & 0xffffu);
    int ceqB = (int)(packB >> 16);
    int neededB = 5 - cltB;
    bool allEqB = (ceqB == neededB);
    unsigned int selBm = allEqB ? (rawB | eqBm) : rawB;
    int base_slot = 0;
#pragma unroll 4
    for (int t = 0; t < 32; t++) {
        bool take = (selBm >> t) & 1;
        unsigned long long m = __ballot(take);
        if (take) c1idx[gw * 5 + base_slot + mbcnt64(m)] = lane + 64 * t;
        base_slot += (int)__popcll(m);
    }
    if (!allEqB) {
        unsigned int em = eqBm;
        for (int r = 0; r < neededB; r++) {
            int mt = __ffs(em) - 1;
            int mj = (mt >= 0) ? (lane + 64 * mt) : 0x7fffffff;
            int bm = mj;
#pragma unroll
            for (int o = 1; o < 64; o <<= 1) bm = min(bm, __shfl_xor(bm, o));
            if (mj == bm && mt >= 0) {
                em &= ~(1u << mt);
                c1idx[gw * 5 + base_slot + r] = bm;
            }
        }
    }
}

// ------------------------------------- fp32 -> fp16 hi/lo split + squared norms
__global__ __launch_bounds__(256) void k_split(const float* __restrict__ X,
                                               half_t* __restrict__ Xh,
                                               half_t* __restrict__ Xl,
                                               float* __restrict__ s) {
    int row = (blockIdx.x * 256 + threadIdx.x) >> 6;
    int lane = threadIdx.x & 63;
    float x = X[(size_t)row * 64 + lane];
    half_t h = (half_t)x;
    half_t l = (half_t)(x - (float)h);
    Xh[(size_t)row * 64 + lane] = h;
    Xl[(size_t)row * 64 + lane] = l;
    float ss = x * x;
#pragma unroll
    for (int o = 1; o < 64; o <<= 1) ss += __shfl_xor(ss, o);
    if (lane == 0) s[row] = ss;
}

// ----------------------------------------- node-level layer-1 split: p = x(Wa-Wb)+b1, q = x Wb
template <int F, int C>
__global__ __launch_bounds__(256, 4) void k_pq(const float* __restrict__ X,
                                               const float* __restrict__ w1,
                                               const float* __restrict__ b1,
                                               float* __restrict__ p,
                                               float* __restrict__ q) {
    constexpr int FS = F + 4;
    __shared__ __align__(16) float Xs[64 * FS];
    __shared__ __align__(16) float Ws[64 * FS];
    int nbase = blockIdx.x * 64;
    int cchunk = blockIdx.y;
    int tx = threadIdx.x & 15, ty = threadIdx.x >> 4;
    for (int idx = threadIdx.x; idx < 64 * (F / 4); idx += 256) {
        int r = idx / (F / 4), fq = idx % (F / 4);
        float4 v = ((const float4*)(X + (size_t)(nbase + r) * F))[fq];
        *(float4*)&Xs[r * FS + fq * 4] = v;
    }
    for (int idx = threadIdx.x; idx < 64 * F; idx += 256) {
        int f = idx >> 6, cl = idx & 63;
        int ccg = cchunk * 64 + cl;
        float v;
        if (ccg < C) v = w1[f * C + ccg] - w1[(F + f) * C + ccg];
        else         v = w1[(F + f) * C + (ccg - C)];
        Ws[cl * FS + f] = v;
    }
    __syncthreads();
    float acc[4][4];
#pragma unroll
    for (int a = 0; a < 4; a++)
#pragma unroll
        for (int b = 0; b < 4; b++) acc[a][b] = 0.f;
#pragma unroll 2
    for (int fs = 0; fs < F / 4; fs++) {
        float4 xv[4], wv[4];
#pragma unroll
        for (int a = 0; a < 4; a++) xv[a] = *(const float4*)&Xs[(ty + 16 * a) * FS + fs * 4];
#pragma unroll
        for (int b = 0; b < 4; b++) wv[b] = *(const float4*)&Ws[(tx + 16 * b) * FS + fs * 4];
#pragma unroll
        for (int a = 0; a < 4; a++)
#pragma unroll
            for (int b = 0; b < 4; b++) {
                acc[a][b] = fmaf(xv[a].x, wv[b].x, acc[a][b]);
                acc[a][b] = fmaf(xv[a].y, wv[b].y, acc[a][b]);
                acc[a][b] = fmaf(xv[a].z, wv[b].z, acc[a][b]);
                acc[a][b] = fmaf(xv[a].w, wv[b].w, acc[a][b]);
            }
    }
#pragma unroll
    for (int a = 0; a < 4; a++) {
        int n = nbase + ty + 16 * a;
#pragma unroll
        for (int b = 0; b < 4; b++) {
            int ccg = cchunk * 64 + tx + 16 * b;
            if (ccg < C) p[(size_t)n * C + ccg] = acc[a][b] + b1[ccg];
            else         q[(size_t)n * C + (ccg - C)] = acc[a][b];
        }
    }
}

// --------------------------------- per-edge layer 2: h2 = leaky(h1 @ w2 + b2), sum over k=5
template <int C1>
__global__ __launch_bounds__(256, 4) void k_edge(const float* __restrict__ p,
                                                 const float* __restrict__ q,
                                                 const int* __restrict__ cidx,
                                                 const float* __restrict__ w2,
                                                 const float* __restrict__ b2,
                                                 float* __restrict__ Xout) {
    __shared__ __align__(16) float h1[80 * 68];
    __shared__ __align__(16) float w2T[64 * 68];
    int nb = blockIdx.x * 16;
    int gb = (nb >> 11) << 11;  // graph base node
    int tx = threadIdx.x & 15, ty = threadIdx.x >> 4;
    float acc[5][4];
#pragma unroll
    for (int m = 0; m < 5; m++)
#pragma unroll
        for (int n = 0; n < 4; n++) acc[m][n] = 0.f;
#pragma unroll 1
    for (int half = 0; half < C1 / 64; half++) {
        __syncthreads();
        for (int idx = threadIdx.x; idx < 64 * 64; idx += 256) {
            int l = idx >> 6, c = idx & 63;
            w2T[c * 68 + l] = w2[(half * 64 + l) * 64 + c];
        }
        for (int idx = threadIdx.x; idx < 80 * 16; idx += 256) {
            int e = idx >> 4, fq = idx & 15;
            int node = nb + e / 5, kk = e - 5 * (e / 5);
            int j = cidx[node * 5 + kk];
            float4 pv = ((const float4*)(p + (size_t)node * C1 + half * 64))[fq];
            float4 qv = ((const float4*)(q + (size_t)(gb + j) * C1 + half * 64))[fq];
            float4 hv;
            hv.x = lk(pv.x + qv.x); hv.y = lk(pv.y + qv.y);
            hv.z = lk(pv.z + qv.z); hv.w = lk(pv.w + qv.w);
            *(float4*)&h1[e * 68 + fq * 4] = hv;
        }
        __syncthreads();
#pragma unroll 1
        for (int ls = 0; ls < 16; ls++) {
            float4 hv[5], wf[4];
#pragma unroll
            for (int m = 0; m < 5; m++) hv[m] = *(const float4*)&h1[(ty + 16 * m) * 68 + ls * 4];
#pragma unroll
            for (int n = 0; n < 4; n++) wf[n] = *(const float4*)&w2T[(tx + 16 * n) * 68 + ls * 4];
#pragma unroll
            for (int m = 0; m < 5; m++)
#pragma unroll
                for (int n = 0; n < 4; n++) {
                    acc[m][n] = fmaf(hv[m].x, wf[n].x, acc[m][n]);
                    acc[m][n] = fmaf(hv[m].y, wf[n].y, acc[m][n]);
                    acc[m][n] = fmaf(hv[m].z, wf[n].z, acc[m][n]);
                    acc[m][n] = fmaf(hv[m].w, wf[n].w, acc[m][n]);
                }
        }
    }
    float b2r[4];
#pragma unroll
    for (int n = 0; n < 4; n++) b2r[n] = b2[tx + 16 * n];
    __syncthreads();  // all h1 reads done; reuse h1 region for h2
    float* h2 = h1;
#pragma unroll
    for (int m = 0; m < 5; m++)
#pragma unroll
        for (int n = 0; n < 4; n++)
            h2[(ty + 16 * m) * 68 + (tx + 16 * n)] = lk(acc[m][n] + b2r[n]);
    __syncthreads();
#pragma unroll
    for (int rr = 0; rr < 4; rr++) {
        int idx = threadIdx.x + 256 * rr;
        int node = idx >> 6, c = idx & 63;
        float sum = 0.f;
#pragma unroll
        for (int kk = 0; kk < 5; kk++) sum += h2[(node * 5 + kk) * 68 + c];
        Xout[(size_t)(nb + node) * 64 + c] = sum;
    }
}

// --------------------------------------------- knn over F=64 features, top-5 (self incl.)
__global__ __launch_bounds__(256) void k_knn64(const half_t* __restrict__ Xh,
                                               const half_t* __restrict__ Xl,
                                               const float* __restrict__ s,
                                               float2* __restrict__ cand) {
    __shared__ __align__(16) char smem[20480];
    int g = blockIdx.x, it = blockIdx.y, bz = blockIdx.z;
    int gbase = g * 2048, ibase = it * 64;
    int lane = threadIdx.x & 63, wave = threadIdx.x >> 6;
    int m = lane & 15, quad = lane >> 4;

    const half_t* ahp = Xh + (size_t)(gbase + ibase + wave * 16 + m) * 64 + quad * 8;
    const half_t* alp = Xl + (size_t)(gbase + ibase + wave * 16 + m) * 64 + quad * 8;
    half8 Ah0 = *(const half8*)(ahp);
    half8 Ah1 = *(const half8*)(ahp + 32);
    half8 Al0 = *(const half8*)(alp);
    half8 Al1 = *(const half8*)(alp + 32);
    float si_r[4];
#pragma unroll
    for (int reg = 0; reg < 4; reg++)
        si_r[reg] = s[gbase + ibase + wave * 16 + quad * 4 + reg];

    u64 K[4][5];
    float thv[4];
#pragma unroll
    for (int a = 0; a < 4; a++) {
        thv[a] = __builtin_inff();
#pragma unroll
        for (int ss = 0; ss < 5; ss++) K[a][ss] = KINIT;
    }

    int jt0 = bz * 8;
    half8 Pbh0[2], Pbh1[2], Pbl0[2], Pbl1[2];
    float Psj[2];
    {
        int jrow = gbase + jt0 * 64 + m;  // jtl=0, sub=0
        const half_t* bhp = Xh + (size_t)jrow * 64 + quad * 8;
        const half_t* blp = Xl + (size_t)jrow * 64 + quad * 8;
        Pbh0[0] = *(const half8*)(bhp);
        Pbh1[0] = *(const half8*)(bhp + 32);
        Pbl0[0] = *(const half8*)(blp);
        Pbl1[0] = *(const half8*)(blp + 32);
        Psj[0] = s[jrow];
    }

#pragma unroll 1
    for (int jtl = 0; jtl < 8; jtl++) {
        int jt = jt0 + jtl;
#pragma unroll
        for (int reg = 0; reg < 4; reg++) {
            float th = unmono((unsigned int)(K[reg][4] >> 32));
            th = fminf(th, __shfl_xor(th, 1));
            th = fminf(th, __shfl_xor(th, 2));
            th = fminf(th, __shfl_xor(th, 4));
            th = fminf(th, __shfl_xor(th, 8));
            thv[reg] = th;
        }
#pragma unroll
        for (int sub = 0; sub < 4; sub++) {
            int cur = sub & 1, nxt = cur ^ 1;
            if (sub < 3 || jtl < 7) {
                int njt = (sub < 3) ? jt : (jt + 1);
                int nsub = (sub < 3) ? (sub + 1) : 0;
                int jrow = gbase + njt * 64 + nsub * 16 + m;
                const half_t* bhp = Xh + (size_t)jrow * 64 + quad * 8;
                const half_t* blp = Xl + (size_t)jrow * 64 + quad * 8;
                Pbh0[nxt] = *(const half8*)(bhp);
                Pbh1[nxt] = *(const half8*)(bhp + 32);
                Pbl0[nxt] = *(const half8*)(blp);
                Pbl1[nxt] = *(const half8*)(blp + 32);
                Psj[nxt] = s[jrow];
            }
            f32x4 ahh = {0.f, 0.f, 0.f, 0.f};
            f32x4 ahl = {0.f, 0.f, 0.f, 0.f};
            f32x4 alh = {0.f, 0.f, 0.f, 0.f};
            f32x4 all = {0.f, 0.f, 0.f, 0.f};
            ahh = __builtin_amdgcn_mfma_f32_16x16x32_f16(Ah0, Pbh0[cur], ahh, 0, 0, 0);
            ahl = __builtin_amdgcn_mfma_f32_16x16x32_f16(Ah0, Pbl0[cur], ahl, 0, 0, 0);
            alh = __builtin_amdgcn_mfma_f32_16x16x32_f16(Al0, Pbh0[cur], alh, 0, 0, 0);
            all = __builtin_amdgcn_mfma_f32_16x16x32_f16(Al0, Pbl0[cur], all, 0, 0, 0);
            ahh = __builtin_amdgcn_mfma_f32_16x16x32_f16(Ah1, Pbh1[cur], ahh, 0, 0, 0);
            ahl = __builtin_amdgcn_mfma_f32_16x16x32_f16(Ah1, Pbl1[cur], ahl, 0, 0, 0);
            alh = __builtin_amdgcn_mfma_f32_16x16x32_f16(Al1, Pbh1[cur], alh, 0, 0, 0);
            all = __builtin_amdgcn_mfma_f32_16x16x32_f16(Al1, Pbl1[cur], all, 0, 0, 0);
            float sjv = Psj[cur];
            int jv = jt * 64 + sub * 16 + m;
#pragma unroll
            for (int reg = 0; reg < 4; reg++) {
                float dot = ((all[reg] + alh[reg]) + ahl[reg]) + ahh[reg];
                float dv = (si_r[reg] + sjv) - 2.f * dot;
                if (__any(dv <= thv[reg])) {
                    if (dv <= thv[reg]) {
                        u64 nk = pk(dv, jv);
                        if (nk < K[reg][4]) {
                            K[reg][4] = nk;
#pragma unroll
                            for (int ss = 4; ss >= 1; ss--)
                                if (K[reg][ss] < K[reg][ss - 1]) {
                                    u64 t = K[reg][ss]; K[reg][ss] = K[reg][ss - 1]; K[reg][ss - 1] = t;
                                }
                        }
                    }
                }
            }
        }
    }

#pragma unroll
    for (int reg = 0; reg < 4; reg++) {
        u64 pv[5];
#pragma unroll
        for (int ss = 0; ss < 5; ss++) pv[ss] = __shfl_xor(K[reg][ss], 1);
        if ((lane & 1) == 0) {
#pragma unroll
            for (int c = 0; c < 5; c++) {
                if (pv[c] < K[reg][4]) {
                    K[reg][4] = pv[c];
#pragma unroll
                    for (int ss = 4; ss >= 1; ss--)
                        if (K[reg][ss] < K[reg][ss - 1]) {
                            u64 t = K[reg][ss]; K[reg][ss] = K[reg][ss - 1]; K[reg][ss - 1] = t;
                        }
                }
            }
        }
    }

    u64* candk = (u64*)smem;  // 64*40*8 = 20480 B
    int rowbase = wave * 16 + quad * 4;
    if ((lane & 1) == 0) {
#pragma unroll
        for (int reg = 0; reg < 4; reg++)
#pragma unroll
            for (int ss = 0; ss < 5; ss++)
                candk[(rowbase + reg) * 40 + (m >> 1) * 5 + ss] = K[reg][ss];
    }
    __syncthreads();
    if (threadIdx.x < 64) {
        int row = threadIdx.x;
        u64 fk[5];
#pragma unroll
        for (int ss = 0; ss < 5; ss++) fk[ss] = KINIT;
#pragma unroll 1
        for (int c = 0; c < 40; c++) {
            u64 k = candk[row * 40 + c];
            if (k < fk[4]) {
                fk[4] = k;
#pragma unroll
                for (int ss = 4; ss >= 1; ss--)
                    if (fk[ss] < fk[ss - 1]) {
                        u64 t = fk[ss]; fk[ss] = fk[ss - 1]; fk[ss - 1] = t;
                    }
            }
        }
#pragma unroll
        for (int ss = 0; ss < 5; ss++) {
            float2 e;
            e.x = unmono((unsigned int)(fk[ss] >> 32));
            e.y = __int_as_float((int)(unsigned int)(fk[ss] & 0xffffffffu));
            cand[((size_t)(gbase + ibase + row) * 4 + bz) * 5 + ss] = e;
        }
    }
}

// ----------------------------- merge the four j-quarter top-5 lists per row -> cidx
__global__ __launch_bounds__(256) void k_knn_merge(const float2* __restrict__ cand,
                                                   int* __restrict__ cidx) {
    int row = blockIdx.x * 256 + threadIdx.x;
    if (row >= BN) return;
    float fv[5];
    int fj[5];
#pragma unroll
    for (int ss = 0; ss < 5; ss++) { fv[ss] = __builtin_inff(); fj[ss] = 0x7fffffff; }
#pragma unroll
    for (int c = 0; c < 20; c++) {
        float2 e = cand[(size_t)row * 20 + c];
        float dv = e.x;
        int jv = __float_as_int(e.y);
        if (lexlt(dv, jv, fv[4], fj[4])) {
            fv[4] = dv; fj[4] = jv;
#pragma unroll
            for (int ss = 4; ss >= 1; ss--)
                if (lexlt(fv[ss], fj[ss], fv[ss - 1], fj[ss - 1])) {
                    float tv = fv[ss]; fv[ss] = fv[ss - 1]; fv[ss - 1] = tv;
                    int tj = fj[ss]; fj[ss] = fj[ss - 1]; fj[ss - 1] = tj;
                }
        }
    }
#pragma unroll
    for (int ss = 0; ss < 5; ss++) cidx[(size_t)row * 5 + ss] = fj[ss];
}

// ------------------------- weight split: l1w1 [196][512] -> WhT/WlT [512][224] fp16 hi/lo
__global__ __launch_bounds__(256) void k_wsplit(const float* __restrict__ w1,
                                                half_t* __restrict__ WhT,
                                                half_t* __restrict__ WlT) {
    int idx = blockIdx.x * 256 + threadIdx.x;
    if (idx >= 512 * 224) return;
    int c = idx / 224, f = idx - c * 224;
    float v = (f < 196) ? w1[(size_t)f * 512 + c] : 0.f;
    half_t h = (half_t)v;
    WhT[(size_t)c * 224 + f] = h;
    WlT[(size_t)c * 224 + f] = (half_t)(v - (float)h);
}

// ------------------------- feature split: concat(xx,x1,x2,x3) -> Fh/Fl [BN][224]
__global__ __launch_bounds__(256) void k_fsplit(const float* __restrict__ xx,
                                                const float* __restrict__ x1,
                                                const float* __restrict__ x2,
                                                const float* __restrict__ x3,
                                                half_t* __restrict__ Fh,
                                                half_t* __restrict__ Fl) {
    int nb = blockIdx.x * 64;
    for (int idx = threadIdx.x; idx < 64 * 56; idx += 256) {
        int r = idx / 56, sg = idx - r * 56;
        int node = nb + r;
        float4 v;
        if (sg == 0)       v = ((const float4*)xx)[node];
        else if (sg < 17)  v = ((const float4*)(x1 + (size_t)node * 64))[sg - 1];
        else if (sg < 33)  v = ((const float4*)(x2 + (size_t)node * 64))[sg - 17];
        else if (sg < 49)  v = ((const float4*)(x3 + (size_t)node * 64))[sg - 33];
        else { v.x = 0.f; v.y = 0.f; v.z = 0.f; v.w = 0.f; }
        float f0 = v.x, f1 = v.y, f2 = v.z, f3 = v.w;
        half_t h0 = (half_t)f0, h1 = (half_t)f1, h2 = (half_t)f2, h3 = (half_t)f3;
        half4 hv = {h0, h1, h2, h3};
        half4 lv = {(half_t)(f0 - (float)h0), (half_t)(f1 - (float)h1),
                    (half_t)(f2 - (float)h2), (half_t)(f3 - (float)h3)};
        *(half4*)(Fh + (size_t)node * 224 + sg * 4) = hv;
        *(half4*)(Fl + (size_t)node * 224 + sg * 4) = lv;
    }
}

// ------------------------- lin1 layer1 via split-fp16 MFMA + leaky + mean-pool partial
__global__ __launch_bounds__(256) void k_lin1m(const half_t* __restrict__ Fh,
                                               const half_t* __restrict__ Fl,
                                               const half_t* __restrict__ WhT,
                                               const half_t* __restrict__ WlT,
                                               const float* __restrict__ b1,
                                               float* __restrict__ Hpart) {
    __shared__ __align__(16) half_t Bh[16 * 232];
    __shared__ __align__(16) half_t Bl[16 * 232];
    __shared__ float pool[4][512];
    int zb = blockIdx.x, g = blockIdx.y;
    int lane = threadIdx.x & 63, wave = threadIdx.x >> 6;
    int m = lane & 15, quad = lane >> 4;
    for (int i = threadIdx.x; i < 4 * 512; i += 256) ((float*)pool)[i] = 0.f;
    int node = g * 2048 + zb * 64 + wave * 16 + m;
    const half_t* fh = Fh + (size_t)node * 224 + quad * 8;
    const half_t* fl = Fl + (size_t)node * 224 + quad * 8;
    half8 Ah[7], Al[7];
#pragma unroll
    for (int ks = 0; ks < 7; ks++) {
        Ah[ks] = *(const half8*)(fh + ks * 32);
        Al[ks] = *(const half8*)(fl + ks * 32);
    }
    __syncthreads();
#pragma unroll 1
    for (int ct = 0; ct < 32; ct++) {
        for (int idx = threadIdx.x; idx < 448; idx += 256) {
            int r = idx / 28, cc = idx - r * 28;
            *(half8*)&Bh[r * 232 + cc * 8] = *(const half8*)(WhT + (size_t)(ct * 16 + r) * 224 + cc * 8);
            *(half8*)&Bl[r * 232 + cc * 8] = *(const half8*)(WlT + (size_t)(ct * 16 + r) * 224 + cc * 8);
        }
        __syncthreads();
        f32x4 a1 = {0.f, 0.f, 0.f, 0.f};
        f32x4 a2 = {0.f, 0.f, 0.f, 0.f};
#pragma unroll
        for (int ks = 0; ks < 7; ks++) {
            half8 bh = *(const half8*)&Bh[m * 232 + ks * 32 + quad * 8];
            half8 bl = *(const half8*)&Bl[m * 232 + ks * 32 + quad * 8];
            a1 = __builtin_amdgcn_mfma_f32_16x16x32_f16(Ah[ks], bh, a1, 0, 0, 0);
            a2 = __builtin_amdgcn_mfma_f32_16x16x32_f16(Ah[ks], bl, a2, 0, 0, 0);
            a2 = __builtin_amdgcn_mfma_f32_16x16x32_f16(Al[ks], bh, a2, 0, 0, 0);
        }
        float bb = b1[ct * 16 + m];
        float sacc = 0.f;
#pragma unroll
        for (int reg = 0; reg < 4; reg++) sacc += lk((a1[reg] + a2[reg]) + bb);
        sacc += __shfl_xor(sacc, 16);
        sacc += __shfl_xor(sacc, 32);
        if (quad == 0) pool[wave][ct * 16 + m] += sacc;
        __syncthreads();
    }
    for (int c = threadIdx.x; c < 512; c += 256) {
        float v = pool[0][c] + pool[1][c] + pool[2][c] + pool[3][c];
        Hpart[((size_t)zb * 32 + g) * 512 + c] = v;
    }
}

// ------------------------------------------------------------- per-graph head
__global__ __launch_bounds__(256) void k_final(const float* __restrict__ Hpart,
                                               const unsigned int* __restrict__ hpart,
                                               const float* __restrict__ l1w2,
                                               const float* __restrict__ l1b2,
                                               const float* __restrict__ mw1,
                                               const float* __restrict__ mb1,
                                               const float* __restrict__ mw2,
                                               const float* __restrict__ mb2,
                                               float* __restrict__ out) {
    __shared__ float Hb[512];
    __shared__ float z[260];
    __shared__ float y[256];
    __shared__ unsigned int hsum[4];
    int g = blockIdx.x, t = threadIdx.x;
    if (t < 4) hsum[t] = 0;
    __syncthreads();
    unsigned int s0 = 0, s1 = 0, s2 = 0, s3 = 0;
#pragma unroll
    for (int r = 0; r < 8; r++) {
        unsigned int v = hpart[g * 2048 + t + 256 * r];
        s0 += v & 0xffu; s1 += (v >> 8) & 0xffu;
        s2 += (v >> 16) & 0xffu; s3 += (v >> 24) & 0xffu;
    }
    atomicAdd(&hsum[0], s0); atomicAdd(&hsum[1], s1);
    atomicAdd(&hsum[2], s2); atomicAdd(&hsum[3], s3);
#pragma unroll
    for (int half = 0; half < 2; half++) {
        int c = t + 256 * half;
        float v = 0.f;
#pragma unroll
        for (int zz = 0; zz < 32; zz++) v += Hpart[((size_t)zz * 32 + g) * 512 + c];
        Hb[c] = v * (1.f / 2048.f);
    }
    __syncthreads();
    float acc = l1b2[t];
    for (int f = 0; f < 512; f++) acc = fmaf(Hb[f], l1w2[f * 256 + t], acc);
    z[t] = lk(acc);
    if (t < 4) z[256 + t] = lk((float)hsum[t] * (1.f / (2048.f * 50.f)));
    __syncthreads();
    float acc2 = mb1[t];
    for (int f = 0; f < 260; f++) acc2 = fmaf(z[f], mw1[f * 256 + t], acc2);
    y[t] = lk(acc2);
    __syncthreads();
    if (t < 3) {
        float a = mb2[t];
        for (int c = 0; c < 256; c++) a = fmaf(y[c], mw2[c * 3 + t], a);
        out[g * 3 + t] = a;
    }
}

// ------------------------------------------------------------------ launcher
extern "C" void kernel_launch(void* const* d_in, const int* in_sizes, int n_in,
                              void* d_out, int out_size, void* d_ws, size_t ws_size,
                              hipStream_t stream) {
    (void)in_sizes; (void)n_in; (void)out_size; (void)ws_size;
    const float* x    = (const float*)d_in[0];
    const float* pos  = (const float*)d_in[1];
    const float* c1w1 = (const float*)d_in[3];
    const float* c1b1 = (const float*)d_in[4];
    const float* c1w2 = (const float*)d_in[5];
    const float* c1b2 = (const float*)d_in[6];
    const float* c2w1 = (const float*)d_in[7];
    const float* c2b1 = (const float*)d_in[8];
    const float* c2w2 = (const float*)d_in[9];
    const float* c2b2 = (const float*)d_in[10];
    const float* l1w1 = (const float*)d_in[11];
    const float* l1b1 = (const float*)d_in[12];
    const float* l1w2 = (const float*)d_in[13];
    const float* l1b2 = (const float*)d_in[14];
    const float* mw1  = (const float*)d_in[15];
    const float* mb1  = (const float*)d_in[16];
    const float* mw2  = (const float*)d_in[17];
    const float* mb2  = (const float*)d_in[18];
    float* out = (float*)d_out;

    char* w = (char*)d_ws;
    auto alloc = [&](size_t bytes) -> void* {
        void* r = (void*)w;
        w += (bytes + 255) & ~(size_t)255;
        return r;
    };
    float* xx   = (float*)alloc((size_t)BN * 4 * 4);
    float* pbuf = (float*)alloc((size_t)BN * 128 * 4);
    float* qbuf = (float*)alloc((size_t)BN * 128 * 4);
    float* x1   = (float*)alloc((size_t)BN * 64 * 4);
    float* x2   = (float*)alloc((size_t)BN * 64 * 4);
    float* x3   = (float*)alloc((size_t)BN * 64 * 4);
    float* sbuf = (float*)alloc((size_t)BN * 4);
    float* sq4  = (float*)alloc((size_t)BN * 4);
    half_t* xh  = (half_t*)alloc((size_t)BN * 64 * 2);
    half_t* xl  = (half_t*)alloc((size_t)BN * 64 * 2);
    int* c1i    = (int*)alloc((size_t)BN * 5 * 4);
    int* c2i    = (int*)alloc((size_t)BN * 5 * 4);
    int* c3i    = (int*)alloc((size_t)BN * 5 * 4);
    unsigned int* hpart = (unsigned int*)alloc((size_t)BN * 4);
    float* Hpart = (float*)alloc((size_t)32 * 32 * 512 * 4);
    float2* cand = (float2*)alloc((size_t)BN * 20 * 8);
    half_t* Fh  = (half_t*)alloc((size_t)BN * 224 * 2);
    half_t* Fl  = (half_t*)alloc((size_t)BN * 224 * 2);
    half_t* WhT = (half_t*)alloc((size_t)512 * 224 * 2);
    half_t* WlT = (half_t*)alloc((size_t)512 * 224 * 2);
    unsigned int* dupf = (unsigned int*)alloc(32 * 4);

    k_build_xx<<<BN / 256, 256, 0, stream>>>(x, pos, xx, sq4);
    k_dupscan<<<32, 256, 0, stream>>>(xx, dupf);
    k_wsplit<<<(512 * 224 + 255) / 256, 256, 0, stream>>>(l1w1, WhT, WlT);
    k_knn4<<<BN / 4, 256, 0, stream>>>(xx, sq4, dupf, c1i, hpart);
    // conv1
    k_pq<4, 64><<<dim3(BN / 64, 2), 256, 0, stream>>>(xx, c1w1, c1b1, pbuf, qbuf);
    k_edge<64><<<BN / 16, 256, 0, stream>>>(pbuf, qbuf, c1i, c1w2, c1b2, x1);
    // conv2
    k_split<<<BN / 4, 256, 0, stream>>>(x1, xh, xl, sbuf);
    k_knn64<<<dim3(32, 32, 4), 256, 0, stream>>>(xh, xl, sbuf, cand);
    k_knn_merge<<<BN / 256, 256, 0, stream>>>(cand, c2i);
    k_pq<64, 128><<<dim3(BN / 64, 4), 256, 0, stream>>>(x1, c2w1, c2b1, pbuf, qbuf);
    k_edge<128><<<BN / 16, 256, 0, stream>>>(pbuf, qbuf, c2i, c2w2, c2b2, x2);
    // conv3 (shared conv2 weights)
    k_split<<<BN / 4, 256, 0, stream>>>(x2, xh, xl, sbuf);
    k_knn64<<<dim3(32, 32, 4), 256, 0, stream>>>(xh, xl, sbuf, cand);
    k_knn_merge<<<BN / 256, 256, 0, stream>>>(cand, c3i);
    k_pq<64, 128><<<dim3(BN / 64, 4), 256, 0, stream>>>(x2, c2w1, c2b1, pbuf, qbuf);
    k_edge<128><<<BN / 16, 256, 0, stream>>>(pbuf, qbuf, c3i, c2w2, c2b2, x3);
    // lin1 via MFMA: feature split, then fused matmul+leaky+pool, then head
    k_fsplit<<<BN / 64, 256, 0, stream>>>(xx, x1, x2, x3, Fh, Fl);
    k_lin1m<<<dim3(32, 32), 256, 0, stream>>>(Fh, Fl, WhT, WlT, l1b1, Hpart);
    k_final<<<32, 256, 0, stream>>>(Hpart, hpart, l1w2, l1b2, mw1, mb1, mw2, mb2, out);
}

// Round 12
// 1357.689 us; speedup vs baseline: 1.0356x; 1.0356x over previous
//
#include <hip/hip_runtime.h>

static constexpr int B = 32, N = 2048, BN = B * N;

#define DEV static __device__ __forceinline__

typedef _Float16 half_t;
typedef __attribute__((ext_vector_type(8))) _Float16 half8;
typedef __attribute__((ext_vector_type(4))) _Float16 half4;
typedef __attribute__((ext_vector_type(4))) float f32x4;
typedef unsigned long long u64;

DEV float lk(float v) { return v >= 0.f ? v : 0.01f * v; }
DEV bool lexlt(float d1, int j1, float d2, int j2) {
    return d1 < d2 || (d1 == d2 && j1 < j2);
}

DEV unsigned int mono(float f) {
    unsigned int b = __float_as_uint(f);
    return b ^ ((unsigned int)((int)b >> 31) | 0x80000000u);
}
DEV float unmono(unsigned int v) {
    unsigned int b = (v & 0x80000000u) ? (v & 0x7fffffffu) : ~v;
    return __uint_as_float(b);
}
// packed key: (mono(d) << 32) | j  — u64 '<' is EXACTLY lexlt(d,j) for j>=0.
DEV u64 pk(float d, int j) {
    return ((u64)mono(d) << 32) | (unsigned int)j;
}
static constexpr u64 KINIT = 0xFF800000ull << 32 | 0x7fffffffull;  // (inf, 0x7fffffff)

DEV int mbcnt64(unsigned long long m) {
    return __builtin_amdgcn_mbcnt_hi((unsigned)(m >> 32),
                                     __builtin_amdgcn_mbcnt_lo((unsigned)m, 0));
}
// exact reference expression: (sa+sb) - 2*dot  (sb precomputed, bit-identical)
DEV float dist4s(float4 a, float sa, float4 b, float sb) {
    float dt = fmaf(a.x, b.x, fmaf(a.y, b.y, fmaf(a.z, b.z, a.w * b.w)));
    return (sa + sb) - 2.f * dt;
}

// ---------------------------------------------------------------- build xx (+ sq norms)
__global__ __launch_bounds__(256) void k_build_xx(const float* __restrict__ x,
                                                  const float* __restrict__ pos,
                                                  float* __restrict__ xx,
                                                  float* __restrict__ sq) {
    int i = blockIdx.x * 256 + threadIdx.x;
    if (i < BN) {
        float4 v;
        v.x = x[i];
        v.y = pos[3 * i + 0];
        v.z = pos[3 * i + 1];
        v.w = pos[3 * i + 2];
        ((float4*)xx)[i] = v;
        sq[i] = fmaf(v.x, v.x, fmaf(v.y, v.y, fmaf(v.z, v.z, v.w * v.w)));
    }
}

// ------------------------------------------------- knn(F=4) + homophily + conv1 idx
// v4 (round-9 state): u[32] in registers; equality early-out skips A-side
// machinery when no non-self candidate shares any coordinate.
__global__ __launch_bounds__(256, 8) void k_knn4(const float* __restrict__ xx,
                                                 const float* __restrict__ sq,
                                                 int* __restrict__ c1idx,
                                                 unsigned int* __restrict__ hpart) {
    int gw = (blockIdx.x * 256 + threadIdx.x) >> 6;  // global row id
    int lane = threadIdx.x & 63;
    int g = gw >> 11, i = gw & 2047;
    int lane_self = i & 63, t_self = i >> 6;
    const float4* base = ((const float4*)xx) + g * N;
    const float* sqb = sq + g * N;
    float4 xi = base[i];
    float si = sqb[i];

    unsigned int u[32];
    unsigned int L[6];
    unsigned int eqany = 0;
#pragma unroll
    for (int s = 0; s < 6; s++) L[s] = 0xFFFFFFFFu;
#pragma unroll 4
    for (int t = 0; t < 32; t++) {
        float4 xj = base[lane + 64 * t];
        float sj = sqb[lane + 64 * t];
        unsigned int nv = mono(dist4s(xi, si, xj, sj));
        u[t] = nv;
        bool eq = (xj.x == xi.x) | (xj.y == xi.y) | (xj.z == xi.z) | (xj.w == xi.w);
        bool notself = (lane + 64 * t) != i;
        eqany |= (eq && notself) ? (1u << t) : 0u;
#pragma unroll
        for (int s = 0; s < 6; s++) {
            unsigned int lo_ = min(L[s], nv);
            nv = max(L[s], nv);
            L[s] = lo_;
        }
    }
    unsigned int uself = 0x80000000u;  // mono(+0.0f)
    bool haveEq = (__ballot(eqany != 0) != 0ULL);

    unsigned int lo = L[0], hi = L[0];
#pragma unroll
    for (int o = 1; o < 64; o <<= 1) {
        lo = min(lo, (unsigned int)__shfl_xor((int)lo, o));
        hi = max(hi, (unsigned int)__shfl_xor((int)hi, o));
    }
    unsigned int cp = lo ^ hi;
    int msb = cp ? (31 - __builtin_clz(cp)) : -1;
    unsigned int prefix = (msb >= 0) ? (hi & ~((2u << msb) - 1u)) : lo;

    unsigned int vA = prefix, vB = prefix;
    if (haveEq) {
#pragma unroll 1
        for (int bit = msb; bit >= 0; --bit) {
            unsigned int cA = vA | (1u << bit);
            unsigned int cB = vB | (1u << bit);
            int cntA = 0, cntB = 0;
#pragma unroll
            for (int s = 0; s < 6; s++) cntA += (int)__popcll(__ballot(L[s] < cA));
#pragma unroll
            for (int s = 0; s < 5; s++) cntB += (int)__popcll(__ballot(L[s] < cB));
            cntA -= (uself < cA) ? 1 : 0;
            if (cntA < 50) vA = cA;
            if (cntB < 5) vB = cB;
        }
        if (__ballot(L[5] < vA) != 0ULL) {
            vA = prefix;
#pragma unroll 1
            for (int bit = msb; bit >= 0; --bit) {
                unsigned int c = vA | (1u << bit);
                int cnt = 0;
#pragma unroll
                for (int t = 0; t < 32; t++) cnt += (int)__popcll(__ballot(u[t] < c));
                cnt -= (uself < c) ? 1 : 0;
                if (cnt < 50) vA = c;
            }
        }
    } else {
#pragma unroll 1
        for (int bit = msb; bit >= 0; --bit) {
            unsigned int cB = vB | (1u << bit);
            int cntB = 0;
#pragma unroll
            for (int s = 0; s < 5; s++) cntB += (int)__popcll(__ballot(L[s] < cB));
            if (cntB < 5) vB = cB;
        }
    }

    unsigned int rawB = 0, eqBm = 0;
#pragma unroll
    for (int t = 0; t < 32; t++) {
        rawB |= (u[t] < vB ? 1u : 0u) << t;
        eqBm |= (u[t] == vB ? 1u : 0u) << t;
    }
    unsigned int packB = (unsigned)__popc(rawB) | ((unsigned)__popc(eqBm) << 16);

    if (haveEq) {
        unsigned int rawA = 0, eqAm = 0;
#pragma unroll
        for (int t = 0; t < 32; t++) {
            rawA |= (u[t] < vA ? 1u : 0u) << t;
            eqAm |= (u[t] == vA ? 1u : 0u) << t;
        }
        unsigned int packA = (unsigned)__popc(rawA) | ((unsigned)__popc(eqAm) << 16);
#pragma unroll
        for (int o = 1; o < 64; o <<= 1) packA += __shfl_xor(packA, o);
        int cltA = (int)(packA & 0xffffu) - ((uself < vA) ? 1 : 0);
        int ceqA = (int)(packA >> 16) - ((uself == vA) ? 1 : 0);

        int neededA = 50 - cltA;
        bool allEqA = (ceqA == neededA);
        unsigned int selAm = rawA, eqAs = eqAm;
        if (lane == lane_self) {
            selAm &= ~(1u << t_self);
            eqAs &= ~(1u << t_self);
        }
        unsigned int hm = allEqA ? (selAm | eqAs) : selAm;
        int c0 = 0, c1 = 0, c2 = 0, c3 = 0;
        unsigned int mm = hm;
        while (mm) {
            int t = __ffs(mm) - 1;
            mm &= mm - 1;
            float4 xj = base[lane + 64 * t];
            c0 += (xj.x == xi.x) ? 1 : 0;
            c1 += (xj.y == xi.y) ? 1 : 0;
            c2 += (xj.z == xi.z) ? 1 : 0;
            c3 += (xj.w == xi.w) ? 1 : 0;
        }
        if (!allEqA) {
            unsigned int em = eqAs;
            for (int r = 0; r < neededA; r++) {
                int mt = __ffs(em) - 1;
                int mj = (mt >= 0) ? (lane + 64 * mt) : 0x7fffffff;
                int bm = mj;
#pragma unroll
                for (int o = 1; o < 64; o <<= 1) bm = min(bm, __shfl_xor(bm, o));
                if (mj == bm && mt >= 0) {
                    em &= ~(1u << mt);
                    float4 xj = base[lane + 64 * mt];
                    c0 += (xj.x == xi.x) ? 1 : 0;
                    c1 += (xj.y == xi.y) ? 1 : 0;
                    c2 += (xj.z == xi.z) ? 1 : 0;
                    c3 += (xj.w == xi.w) ? 1 : 0;
                }
            }
        }
        unsigned int pc = (unsigned)c0 | ((unsigned)c1 << 8) | ((unsigned)c2 << 16) | ((unsigned)c3 << 24);
#pragma unroll
        for (int o = 1; o < 64; o <<= 1) pc += __shfl_xor(pc, o);
        if (lane == 0) hpart[gw] = pc;
    } else {
        if (lane == 0) hpart[gw] = 0u;
    }

#pragma unroll
    for (int o = 1; o < 64; o <<= 1) packB += __shfl_xor(packB, o);
    int cltB = (int)(packB & 0xffffu);
    int ceqB = (int)(packB >> 16);
    int neededB = 5 - cltB;
    bool allEqB = (ceqB == neededB);
    unsigned int selBm = allEqB ? (rawB | eqBm) : rawB;
    int base_slot = 0;
#pragma unroll 4
    for (int t = 0; t < 32; t++) {
        bool take = (selBm >> t) & 1;
        unsigned long long m = __ballot(take);
        if (take) c1idx[gw * 5 + base_slot + mbcnt64(m)] = lane + 64 * t;
        base_slot += (int)__popcll(m);
    }
    if (!allEqB) {
        unsigned int em = eqBm;
        for (int r = 0; r < neededB; r++) {
            int mt = __ffs(em) - 1;
            int mj = (mt >= 0) ? (lane + 64 * mt) : 0x7fffffff;
            int bm = mj;
#pragma unroll
            for (int o = 1; o < 64; o <<= 1) bm = min(bm, __shfl_xor(bm, o));
            if (mj == bm && mt >= 0) {
                em &= ~(1u << mt);
                c1idx[gw * 5 + base_slot + r] = bm;
            }
        }
    }
}

// ------------------------------------- fp32 -> fp16 hi/lo split + squared norms
__global__ __launch_bounds__(256) void k_split(const float* __restrict__ X,
                                               half_t* __restrict__ Xh,
                                               half_t* __restrict__ Xl,
                                               float* __restrict__ s) {
    int row = (blockIdx.x * 256 + threadIdx.x) >> 6;
    int lane = threadIdx.x & 63;
    float x = X[(size_t)row * 64 + lane];
    half_t h = (half_t)x;
    half_t l = (half_t)(x - (float)h);
    Xh[(size_t)row * 64 + lane] = h;
    Xl[(size_t)row * 64 + lane] = l;
    float ss = x * x;
#pragma unroll
    for (int o = 1; o < 64; o <<= 1) ss += __shfl_xor(ss, o);
    if (lane == 0) s[row] = ss;
}

// ----------------------------------------- node-level layer-1 split: p = x(Wa-Wb)+b1, q = x Wb
template <int F, int C>
__global__ __launch_bounds__(256, 4) void k_pq(const float* __restrict__ X,
                                               const float* __restrict__ w1,
                                               const float* __restrict__ b1,
                                               float* __restrict__ p,
                                               float* __restrict__ q) {
    constexpr int FS = F + 4;
    __shared__ __align__(16) float Xs[64 * FS];
    __shared__ __align__(16) float Ws[64 * FS];
    int nbase = blockIdx.x * 64;
    int cchunk = blockIdx.y;
    int tx = threadIdx.x & 15, ty = threadIdx.x >> 4;
    for (int idx = threadIdx.x; idx < 64 * (F / 4); idx += 256) {
        int r = idx / (F / 4), fq = idx % (F / 4);
        float4 v = ((const float4*)(X + (size_t)(nbase + r) * F))[fq];
        *(float4*)&Xs[r * FS + fq * 4] = v;
    }
    for (int idx = threadIdx.x; idx < 64 * F; idx += 256) {
        int f = idx >> 6, cl = idx & 63;
        int ccg = cchunk * 64 + cl;
        float v;
        if (ccg < C) v = w1[f * C + ccg] - w1[(F + f) * C + ccg];
        else         v = w1[(F + f) * C + (ccg - C)];
        Ws[cl * FS + f] = v;
    }
    __syncthreads();
    float acc[4][4];
#pragma unroll
    for (int a = 0; a < 4; a++)
#pragma unroll
        for (int b = 0; b < 4; b++) acc[a][b] = 0.f;
#pragma unroll 2
    for (int fs = 0; fs < F / 4; fs++) {
        float4 xv[4], wv[4];
#pragma unroll
        for (int a = 0; a < 4; a++) xv[a] = *(const float4*)&Xs[(ty + 16 * a) * FS + fs * 4];
#pragma unroll
        for (int b = 0; b < 4; b++) wv[b] = *(const float4*)&Ws[(tx + 16 * b) * FS + fs * 4];
#pragma unroll
        for (int a = 0; a < 4; a++)
#pragma unroll
            for (int b = 0; b < 4; b++) {
                acc[a][b] = fmaf(xv[a].x, wv[b].x, acc[a][b]);
                acc[a][b] = fmaf(xv[a].y, wv[b].y, acc[a][b]);
                acc[a][b] = fmaf(xv[a].z, wv[b].z, acc[a][b]);
                acc[a][b] = fmaf(xv[a].w, wv[b].w, acc[a][b]);
            }
    }
#pragma unroll
    for (int a = 0; a < 4; a++) {
        int n = nbase + ty + 16 * a;
#pragma unroll
        for (int b = 0; b < 4; b++) {
            int ccg = cchunk * 64 + tx + 16 * b;
            if (ccg < C) p[(size_t)n * C + ccg] = acc[a][b] + b1[ccg];
            else         q[(size_t)n * C + (ccg - C)] = acc[a][b];
        }
    }
}

// --------------------------------- per-edge layer 2: h2 = leaky(h1 @ w2 + b2), sum over k=5
template <int C1>
__global__ __launch_bounds__(256, 4) void k_edge(const float* __restrict__ p,
                                                 const float* __restrict__ q,
                                                 const int* __restrict__ cidx,
                                                 const float* __restrict__ w2,
                                                 const float* __restrict__ b2,
                                                 float* __restrict__ Xout) {
    __shared__ __align__(16) float h1[80 * 68];
    __shared__ __align__(16) float w2T[64 * 68];
    int nb = blockIdx.x * 16;
    int gb = (nb >> 11) << 11;  // graph base node
    int tx = threadIdx.x & 15, ty = threadIdx.x >> 4;
    float acc[5][4];
#pragma unroll
    for (int m = 0; m < 5; m++)
#pragma unroll
        for (int n = 0; n < 4; n++) acc[m][n] = 0.f;
#pragma unroll 1
    for (int half = 0; half < C1 / 64; half++) {
        __syncthreads();
        for (int idx = threadIdx.x; idx < 64 * 64; idx += 256) {
            int l = idx >> 6, c = idx & 63;
            w2T[c * 68 + l] = w2[(half * 64 + l) * 64 + c];
        }
        for (int idx = threadIdx.x; idx < 80 * 16; idx += 256) {
            int e = idx >> 4, fq = idx & 15;
            int node = nb + e / 5, kk = e - 5 * (e / 5);
            int j = cidx[node * 5 + kk];
            float4 pv = ((const float4*)(p + (size_t)node * C1 + half * 64))[fq];
            float4 qv = ((const float4*)(q + (size_t)(gb + j) * C1 + half * 64))[fq];
            float4 hv;
            hv.x = lk(pv.x + qv.x); hv.y = lk(pv.y + qv.y);
            hv.z = lk(pv.z + qv.z); hv.w = lk(pv.w + qv.w);
            *(float4*)&h1[e * 68 + fq * 4] = hv;
        }
        __syncthreads();
#pragma unroll 1
        for (int ls = 0; ls < 16; ls++) {
            float4 hv[5], wf[4];
#pragma unroll
            for (int m = 0; m < 5; m++) hv[m] = *(const float4*)&h1[(ty + 16 * m) * 68 + ls * 4];
#pragma unroll
            for (int n = 0; n < 4; n++) wf[n] = *(const float4*)&w2T[(tx + 16 * n) * 68 + ls * 4];
#pragma unroll
            for (int m = 0; m < 5; m++)
#pragma unroll
                for (int n = 0; n < 4; n++) {
                    acc[m][n] = fmaf(hv[m].x, wf[n].x, acc[m][n]);
                    acc[m][n] = fmaf(hv[m].y, wf[n].y, acc[m][n]);
                    acc[m][n] = fmaf(hv[m].z, wf[n].z, acc[m][n]);
                    acc[m][n] = fmaf(hv[m].w, wf[n].w, acc[m][n]);
                }
        }
    }
    float b2r[4];
#pragma unroll
    for (int n = 0; n < 4; n++) b2r[n] = b2[tx + 16 * n];
    __syncthreads();  // all h1 reads done; reuse h1 region for h2
    float* h2 = h1;
#pragma unroll
    for (int m = 0; m < 5; m++)
#pragma unroll
        for (int n = 0; n < 4; n++)
            h2[(ty + 16 * m) * 68 + (tx + 16 * n)] = lk(acc[m][n] + b2r[n]);
    __syncthreads();
#pragma unroll
    for (int rr = 0; rr < 4; rr++) {
        int idx = threadIdx.x + 256 * rr;
        int node = idx >> 6, c = idx & 63;
        float sum = 0.f;
#pragma unroll
        for (int kk = 0; kk < 5; kk++) sum += h2[(node * 5 + kk) * 68 + c];
        Xout[(size_t)(nb + node) * 64 + c] = sum;
    }
}

// --------------------------------------------- knn over F=64 features, top-5 (self incl.)
// v7: incremental addressing — the (jtl,sub) walk advances jrow by exactly +16
// rows per step, so B-pointers advance by a constant +1024 halfs (+16 floats
// for norms, +16 for jv). Replaces per-sub 64-bit address recompute with
// running-pointer adds. All load addresses and arithmetic bit-identical.
__global__ __launch_bounds__(256) void k_knn64(const half_t* __restrict__ Xh,
                                               const half_t* __restrict__ Xl,
                                               const float* __restrict__ s,
                                               float2* __restrict__ cand) {
    __shared__ __align__(16) char smem[20480];
    int g = blockIdx.x, it = blockIdx.y, bz = blockIdx.z;
    int gbase = g * 2048, ibase = it * 64;
    int lane = threadIdx.x & 63, wave = threadIdx.x >> 6;
    int m = lane & 15, quad = lane >> 4;

    const half_t* ahp = Xh + (size_t)(gbase + ibase + wave * 16 + m) * 64 + quad * 8;
    const half_t* alp = Xl + (size_t)(gbase + ibase + wave * 16 + m) * 64 + quad * 8;
    half8 Ah0 = *(const half8*)(ahp);
    half8 Ah1 = *(const half8*)(ahp + 32);
    half8 Al0 = *(const half8*)(alp);
    half8 Al1 = *(const half8*)(alp + 32);
    float si_r[4];
#pragma unroll
    for (int reg = 0; reg < 4; reg++)
        si_r[reg] = s[gbase + ibase + wave * 16 + quad * 4 + reg];

    u64 K[4][5];
    float thv[4];
#pragma unroll
    for (int a = 0; a < 4; a++) {
        thv[a] = __builtin_inff();
#pragma unroll
        for (int ss = 0; ss < 5; ss++) K[a][ss] = KINIT;
    }

    int jt0 = bz * 8;
    // running pointers: advance +1024 halfs (16 rows) / +16 floats per step
    const half_t* pbh = Xh + (size_t)(gbase + jt0 * 64 + m) * 64 + quad * 8;
    const half_t* pbl = Xl + (size_t)(gbase + jt0 * 64 + m) * 64 + quad * 8;
    const float* psn = s + gbase + jt0 * 64 + m;
    int jvc = jt0 * 64 + m;

    half8 Pbh0[2], Pbh1[2], Pbl0[2], Pbl1[2];
    float Psj[2];
    // initial prefetch (step 0)
    Pbh0[0] = *(const half8*)(pbh);
    Pbh1[0] = *(const half8*)(pbh + 32);
    Pbl0[0] = *(const half8*)(pbl);
    Pbl1[0] = *(const half8*)(pbl + 32);
    Psj[0] = *psn;
    pbh += 1024; pbl += 1024; psn += 16;

#pragma unroll 1
    for (int jtl = 0; jtl < 8; jtl++) {
#pragma unroll
        for (int reg = 0; reg < 4; reg++) {
            float th = unmono((unsigned int)(K[reg][4] >> 32));
            th = fminf(th, __shfl_xor(th, 1));
            th = fminf(th, __shfl_xor(th, 2));
            th = fminf(th, __shfl_xor(th, 4));
            th = fminf(th, __shfl_xor(th, 8));
            thv[reg] = th;
        }
#pragma unroll
        for (int sub = 0; sub < 4; sub++) {
            int cur = sub & 1, nxt = cur ^ 1;
            if (sub < 3 || jtl < 7) {
                Pbh0[nxt] = *(const half8*)(pbh);
                Pbh1[nxt] = *(const half8*)(pbh + 32);
                Pbl0[nxt] = *(const half8*)(pbl);
                Pbl1[nxt] = *(const half8*)(pbl + 32);
                Psj[nxt] = *psn;
                pbh += 1024; pbl += 1024; psn += 16;
            }
            f32x4 ahh = {0.f, 0.f, 0.f, 0.f};
            f32x4 ahl = {0.f, 0.f, 0.f, 0.f};
            f32x4 alh = {0.f, 0.f, 0.f, 0.f};
            f32x4 all = {0.f, 0.f, 0.f, 0.f};
            ahh = __builtin_amdgcn_mfma_f32_16x16x32_f16(Ah0, Pbh0[cur], ahh, 0, 0, 0);
            ahl = __builtin_amdgcn_mfma_f32_16x16x32_f16(Ah0, Pbl0[cur], ahl, 0, 0, 0);
            alh = __builtin_amdgcn_mfma_f32_16x16x32_f16(Al0, Pbh0[cur], alh, 0, 0, 0);
            all = __builtin_amdgcn_mfma_f32_16x16x32_f16(Al0, Pbl0[cur], all, 0, 0, 0);
            ahh = __builtin_amdgcn_mfma_f32_16x16x32_f16(Ah1, Pbh1[cur], ahh, 0, 0, 0);
            ahl = __builtin_amdgcn_mfma_f32_16x16x32_f16(Ah1, Pbl1[cur], ahl, 0, 0, 0);
            alh = __builtin_amdgcn_mfma_f32_16x16x32_f16(Al1, Pbh1[cur], alh, 0, 0, 0);
            all = __builtin_amdgcn_mfma_f32_16x16x32_f16(Al1, Pbl1[cur], all, 0, 0, 0);
            float sjv = Psj[cur];
            int jv = jvc;
            jvc += 16;
#pragma unroll
            for (int reg = 0; reg < 4; reg++) {
                float dot = ((all[reg] + alh[reg]) + ahl[reg]) + ahh[reg];
                float dv = (si_r[reg] + sjv) - 2.f * dot;
                if (__any(dv <= thv[reg])) {
                    if (dv <= thv[reg]) {
                        u64 nk = pk(dv, jv);
                        if (nk < K[reg][4]) {
                            K[reg][4] = nk;
#pragma unroll
                            for (int ss = 4; ss >= 1; ss--)
                                if (K[reg][ss] < K[reg][ss - 1]) {
                                    u64 t = K[reg][ss]; K[reg][ss] = K[reg][ss - 1]; K[reg][ss - 1] = t;
                                }
                        }
                    }
                }
            }
        }
    }

#pragma unroll
    for (int reg = 0; reg < 4; reg++) {
        u64 pv[5];
#pragma unroll
        for (int ss = 0; ss < 5; ss++) pv[ss] = __shfl_xor(K[reg][ss], 1);
        if ((lane & 1) == 0) {
#pragma unroll
            for (int c = 0; c < 5; c++) {
                if (pv[c] < K[reg][4]) {
                    K[reg][4] = pv[c];
#pragma unroll
                    for (int ss = 4; ss >= 1; ss--)
                        if (K[reg][ss] < K[reg][ss - 1]) {
                            u64 t = K[reg][ss]; K[reg][ss] = K[reg][ss - 1]; K[reg][ss - 1] = t;
                        }
                }
            }
        }
    }

    u64* candk = (u64*)smem;  // 64*40*8 = 20480 B
    int rowbase = wave * 16 + quad * 4;
    if ((lane & 1) == 0) {
#pragma unroll
        for (int reg = 0; reg < 4; reg++)
#pragma unroll
            for (int ss = 0; ss < 5; ss++)
                candk[(rowbase + reg) * 40 + (m >> 1) * 5 + ss] = K[reg][ss];
    }
    __syncthreads();
    if (threadIdx.x < 64) {
        int row = threadIdx.x;
        u64 fk[5];
#pragma unroll
        for (int ss = 0; ss < 5; ss++) fk[ss] = KINIT;
#pragma unroll 1
        for (int c = 0; c < 40; c++) {
            u64 k = candk[row * 40 + c];
            if (k < fk[4]) {
                fk[4] = k;
#pragma unroll
                for (int ss = 4; ss >= 1; ss--)
                    if (fk[ss] < fk[ss - 1]) {
                        u64 t = fk[ss]; fk[ss] = fk[ss - 1]; fk[ss - 1] = t;
                    }
            }
        }
#pragma unroll
        for (int ss = 0; ss < 5; ss++) {
            float2 e;
            e.x = unmono((unsigned int)(fk[ss] >> 32));
            e.y = __int_as_float((int)(unsigned int)(fk[ss] & 0xffffffffu));
            cand[((size_t)(gbase + ibase + row) * 4 + bz) * 5 + ss] = e;
        }
    }
}

// ----------------------------- merge the four j-quarter top-5 lists per row -> cidx
__global__ __launch_bounds__(256) void k_knn_merge(const float2* __restrict__ cand,
                                                   int* __restrict__ cidx) {
    int row = blockIdx.x * 256 + threadIdx.x;
    if (row >= BN) return;
    float fv[5];
    int fj[5];
#pragma unroll
    for (int ss = 0; ss < 5; ss++) { fv[ss] = __builtin_inff(); fj[ss] = 0x7fffffff; }
#pragma unroll
    for (int c = 0; c < 20; c++) {
        float2 e = cand[(size_t)row * 20 + c];
        float dv = e.x;
        int jv = __float_as_int(e.y);
        if (lexlt(dv, jv, fv[4], fj[4])) {
            fv[4] = dv; fj[4] = jv;
#pragma unroll
            for (int ss = 4; ss >= 1; ss--)
                if (lexlt(fv[ss], fj[ss], fv[ss - 1], fj[ss - 1])) {
                    float tv = fv[ss]; fv[ss] = fv[ss - 1]; fv[ss - 1] = tv;
                    int tj = fj[ss]; fj[ss] = fj[ss - 1]; fj[ss - 1] = tj;
                }
        }
    }
#pragma unroll
    for (int ss = 0; ss < 5; ss++) cidx[(size_t)row * 5 + ss] = fj[ss];
}

// ------------------------- weight split: l1w1 [196][512] -> WhT/WlT [512][224] fp16 hi/lo
__global__ __launch_bounds__(256) void k_wsplit(const float* __restrict__ w1,
                                                half_t* __restrict__ WhT,
                                                half_t* __restrict__ WlT) {
    int idx = blockIdx.x * 256 + threadIdx.x;
    if (idx >= 512 * 224) return;
    int c = idx / 224, f = idx - c * 224;
    float v = (f < 196) ? w1[(size_t)f * 512 + c] : 0.f;
    half_t h = (half_t)v;
    WhT[(size_t)c * 224 + f] = h;
    WlT[(size_t)c * 224 + f] = (half_t)(v - (float)h);
}

// ------------------------- feature split: concat(xx,x1,x2,x3) -> Fh/Fl [BN][224]
__global__ __launch_bounds__(256) void k_fsplit(const float* __restrict__ xx,
                                                const float* __restrict__ x1,
                                                const float* __restrict__ x2,
                                                const float* __restrict__ x3,
                                                half_t* __restrict__ Fh,
                                                half_t* __restrict__ Fl) {
    int nb = blockIdx.x * 64;
    for (int idx = threadIdx.x; idx < 64 * 56; idx += 256) {
        int r = idx / 56, sg = idx - r * 56;
        int node = nb + r;
        float4 v;
        if (sg == 0)       v = ((const float4*)xx)[node];
        else if (sg < 17)  v = ((const float4*)(x1 + (size_t)node * 64))[sg - 1];
        else if (sg < 33)  v = ((const float4*)(x2 + (size_t)node * 64))[sg - 17];
        else if (sg < 49)  v = ((const float4*)(x3 + (size_t)node * 64))[sg - 33];
        else { v.x = 0.f; v.y = 0.f; v.z = 0.f; v.w = 0.f; }
        float f0 = v.x, f1 = v.y, f2 = v.z, f3 = v.w;
        half_t h0 = (half_t)f0, h1 = (half_t)f1, h2 = (half_t)f2, h3 = (half_t)f3;
        half4 hv = {h0, h1, h2, h3};
        half4 lv = {(half_t)(f0 - (float)h0), (half_t)(f1 - (float)h1),
                    (half_t)(f2 - (float)h2), (half_t)(f3 - (float)h3)};
        *(half4*)(Fh + (size_t)node * 224 + sg * 4) = hv;
        *(half4*)(Fl + (size_t)node * 224 + sg * 4) = lv;
    }
}

// ------------------------- lin1 layer1 via split-fp16 MFMA + leaky + mean-pool partial
__global__ __launch_bounds__(256) void k_lin1m(const half_t* __restrict__ Fh,
                                               const half_t* __restrict__ Fl,
                                               const half_t* __restrict__ WhT,
                                               const half_t* __restrict__ WlT,
                                               const float* __restrict__ b1,
                                               float* __restrict__ Hpart) {
    __shared__ __align__(16) half_t Bh[16 * 232];
    __shared__ __align__(16) half_t Bl[16 * 232];
    __shared__ float pool[4][512];
    int zb = blockIdx.x, g = blockIdx.y;
    int lane = threadIdx.x & 63, wave = threadIdx.x >> 6;
    int m = lane & 15, quad = lane >> 4;
    for (int i = threadIdx.x; i < 4 * 512; i += 256) ((float*)pool)[i] = 0.f;
    int node = g * 2048 + zb * 64 + wave * 16 + m;
    const half_t* fh = Fh + (size_t)node * 224 + quad * 8;
    const half_t* fl = Fl + (size_t)node * 224 + quad * 8;
    half8 Ah[7], Al[7];
#pragma unroll
    for (int ks = 0; ks < 7; ks++) {
        Ah[ks] = *(const half8*)(fh + ks * 32);
        Al[ks] = *(const half8*)(fl + ks * 32);
    }
    __syncthreads();
#pragma unroll 1
    for (int ct = 0; ct < 32; ct++) {
        for (int idx = threadIdx.x; idx < 448; idx += 256) {
            int r = idx / 28, cc = idx - r * 28;
            *(half8*)&Bh[r * 232 + cc * 8] = *(const half8*)(WhT + (size_t)(ct * 16 + r) * 224 + cc * 8);
            *(half8*)&Bl[r * 232 + cc * 8] = *(const half8*)(WlT + (size_t)(ct * 16 + r) * 224 + cc * 8);
        }
        __syncthreads();
        f32x4 a1 = {0.f, 0.f, 0.f, 0.f};
        f32x4 a2 = {0.f, 0.f, 0.f, 0.f};
#pragma unroll
        for (int ks = 0; ks < 7; ks++) {
            half8 bh = *(const half8*)&Bh[m * 232 + ks * 32 + quad * 8];
            half8 bl = *(const half8*)&Bl[m * 232 + ks * 32 + quad * 8];
            a1 = __builtin_amdgcn_mfma_f32_16x16x32_f16(Ah[ks], bh, a1, 0, 0, 0);
            a2 = __builtin_amdgcn_mfma_f32_16x16x32_f16(Ah[ks], bl, a2, 0, 0, 0);
            a2 = __builtin_amdgcn_mfma_f32_16x16x32_f16(Al[ks], bh, a2, 0, 0, 0);
        }
        float bb = b1[ct * 16 + m];
        float sacc = 0.f;
#pragma unroll
        for (int reg = 0; reg < 4; reg++) sacc += lk((a1[reg] + a2[reg]) + bb);
        sacc += __shfl_xor(sacc, 16);
        sacc += __shfl_xor(sacc, 32);
        if (quad == 0) pool[wave][ct * 16 + m] += sacc;
        __syncthreads();
    }
    for (int c = threadIdx.x; c < 512; c += 256) {
        float v = pool[0][c] + pool[1][c] + pool[2][c] + pool[3][c];
        Hpart[((size_t)zb * 32 + g) * 512 + c] = v;
    }
}

// ------------------------------------------------------------- per-graph head
__global__ __launch_bounds__(256) void k_final(const float* __restrict__ Hpart,
                                               const unsigned int* __restrict__ hpart,
                                               const float* __restrict__ l1w2,
                                               const float* __restrict__ l1b2,
                                               const float* __restrict__ mw1,
                                               const float* __restrict__ mb1,
                                               const float* __restrict__ mw2,
                                               const float* __restrict__ mb2,
                                               float* __restrict__ out) {
    __shared__ float Hb[512];
    __shared__ float z[260];
    __shared__ float y[256];
    __shared__ unsigned int hsum[4];
    int g = blockIdx.x, t = threadIdx.x;
    if (t < 4) hsum[t] = 0;
    __syncthreads();
    unsigned int s0 = 0, s1 = 0, s2 = 0, s3 = 0;
#pragma unroll
    for (int r = 0; r < 8; r++) {
        unsigned int v = hpart[g * 2048 + t + 256 * r];
        s0 += v & 0xffu; s1 += (v >> 8) & 0xffu;
        s2 += (v >> 16) & 0xffu; s3 += (v >> 24) & 0xffu;
    }
    atomicAdd(&hsum[0], s0); atomicAdd(&hsum[1], s1);
    atomicAdd(&hsum[2], s2); atomicAdd(&hsum[3], s3);
#pragma unroll
    for (int half = 0; half < 2; half++) {
        int c = t + 256 * half;
        float v = 0.f;
#pragma unroll
        for (int zz = 0; zz < 32; zz++) v += Hpart[((size_t)zz * 32 + g) * 512 + c];
        Hb[c] = v * (1.f / 2048.f);
    }
    __syncthreads();
    float acc = l1b2[t];
    for (int f = 0; f < 512; f++) acc = fmaf(Hb[f], l1w2[f * 256 + t], acc);
    z[t] = lk(acc);
    if (t < 4) z[256 + t] = lk((float)hsum[t] * (1.f / (2048.f * 50.f)));
    __syncthreads();
    float acc2 = mb1[t];
    for (int f = 0; f < 260; f++) acc2 = fmaf(z[f], mw1[f * 256 + t], acc2);
    y[t] = lk(acc2);
    __syncthreads();
    if (t < 3) {
        float a = mb2[t];
        for (int c = 0; c < 256; c++) a = fmaf(y[c], mw2[c * 3 + t], a);
        out[g * 3 + t] = a;
    }
}

// ------------------------------------------------------------------ launcher
extern "C" void kernel_launch(void* const* d_in, const int* in_sizes, int n_in,
                              void* d_out, int out_size, void* d_ws, size_t ws_size,
                              hipStream_t stream) {
    (void)in_sizes; (void)n_in; (void)out_size; (void)ws_size;
    const float* x    = (const float*)d_in[0];
    const float* pos  = (const float*)d_in[1];
    const float* c1w1 = (const float*)d_in[3];
    const float* c1b1 = (const float*)d_in[4];
    const float* c1w2 = (const float*)d_in[5];
    const float* c1b2 = (const float*)d_in[6];
    const float* c2w1 = (const float*)d_in[7];
    const float* c2b1 = (const float*)d_in[8];
    const float* c2w2 = (const float*)d_in[9];
    const float* c2b2 = (const float*)d_in[10];
    const float* l1w1 = (const float*)d_in[11];
    const float* l1b1 = (const float*)d_in[12];
    const float* l1w2 = (const float*)d_in[13];
    const float* l1b2 = (const float*)d_in[14];
    const float* mw1  = (const float*)d_in[15];
    const float* mb1  = (const float*)d_in[16];
    const float* mw2  = (const float*)d_in[17];
    const float* mb2  = (const float*)d_in[18];
    float* out = (float*)d_out;

    char* w = (char*)d_ws;
    auto alloc = [&](size_t bytes) -> void* {
        void* r = (void*)w;
        w += (bytes + 255) & ~(size_t)255;
        return r;
    };
    float* xx   = (float*)alloc((size_t)BN * 4 * 4);
    float* pbuf = (float*)alloc((size_t)BN * 128 * 4);
    float* qbuf = (float*)alloc((size_t)BN * 128 * 4);
    float* x1   = (float*)alloc((size_t)BN * 64 * 4);
    float* x2   = (float*)alloc((size_t)BN * 64 * 4);
    float* x3   = (float*)alloc((size_t)BN * 64 * 4);
    float* sbuf = (float*)alloc((size_t)BN * 4);
    float* sq4  = (float*)alloc((size_t)BN * 4);
    half_t* xh  = (half_t*)alloc((size_t)BN * 64 * 2);
    half_t* xl  = (half_t*)alloc((size_t)BN * 64 * 2);
    int* c1i    = (int*)alloc((size_t)BN * 5 * 4);
    int* c2i    = (int*)alloc((size_t)BN * 5 * 4);
    int* c3i    = (int*)alloc((size_t)BN * 5 * 4);
    unsigned int* hpart = (unsigned int*)alloc((size_t)BN * 4);
    float* Hpart = (float*)alloc((size_t)32 * 32 * 512 * 4);
    float2* cand = (float2*)alloc((size_t)BN * 20 * 8);
    half_t* Fh  = (half_t*)alloc((size_t)BN * 224 * 2);
    half_t* Fl  = (half_t*)alloc((size_t)BN * 224 * 2);
    half_t* WhT = (half_t*)alloc((size_t)512 * 224 * 2);
    half_t* WlT = (half_t*)alloc((size_t)512 * 224 * 2);

    k_build_xx<<<BN / 256, 256, 0, stream>>>(x, pos, xx, sq4);
    k_wsplit<<<(512 * 224 + 255) / 256, 256, 0, stream>>>(l1w1, WhT, WlT);
    k_knn4<<<BN / 4, 256, 0, stream>>>(xx, sq4, c1i, hpart);
    // conv1
    k_pq<4, 64><<<dim3(BN / 64, 2), 256, 0, stream>>>(xx, c1w1, c1b1, pbuf, qbuf);
    k_edge<64><<<BN / 16, 256, 0, stream>>>(pbuf, qbuf, c1i, c1w2, c1b2, x1);
    // conv2
    k_split<<<BN / 4, 256, 0, stream>>>(x1, xh, xl, sbuf);
    k_knn64<<<dim3(32, 32, 4), 256, 0, stream>>>(xh, xl, sbuf, cand);
    k_knn_merge<<<BN / 256, 256, 0, stream>>>(cand, c2i);
    k_pq<64, 128><<<dim3(BN / 64, 4), 256, 0, stream>>>(x1, c2w1, c2b1, pbuf, qbuf);
    k_edge<128><<<BN / 16, 256, 0, stream>>>(pbuf, qbuf, c2i, c2w2, c2b2, x2);
    // conv3 (shared conv2 weights)
    k_split<<<BN / 4, 256, 0, stream>>>(x2, xh, xl, sbuf);
    k_knn64<<<dim3(32, 32, 4), 256, 0, stream>>>(xh, xl, sbuf, cand);
    k_knn_merge<<<BN / 256, 256, 0, stream>>>(cand, c3i);
    k_pq<64, 128><<<dim3(BN / 64, 4), 256, 0, stream>>>(x2, c2w1, c2b1, pbuf, qbuf);
    k_edge<128><<<BN / 16, 256, 0, stream>>>(pbuf, qbuf, c3i, c2w2, c2b2, x3);
    // lin1 via MFMA: feature split, then fused matmul+leaky+pool, then head
    k_fsplit<<<BN / 64, 256, 0, stream>>>(xx, x1, x2, x3, Fh, Fl);
    k_lin1m<<<dim3(32, 32), 256, 0, stream>>>(Fh, Fl, WhT, WlT, l1b1, Hpart);
    k_final<<<32, 256, 0, stream>>>(Hpart, hpart, l1w2, l1b2, mw1, mb1, mw2, mb2, out);
}